// Round 8
// baseline (132.797 us; speedup 1.0000x reference)
//
#include <hip/hip_runtime.h>
#include <math.h>

#define NTOK 16384
#define DDIM 2048
#define NEXP 64
#define MT   128                 // tokens per stage-1 block
#define KSPLIT 8
#define KRANGE (DDIM / KSPLIT)   // 256
#define KC   16                  // k per LDS chunk
#define NCH  (KRANGE / KC)       // 16

// ws layout (floats): [0..63] f counts, [64..127] P sums, [128] sum lse^2,
// [256 ...] partial logits: [KSPLIT][NTOK][NEXP]
#define PART_OFF 256

// x-tile LDS: [128 tok][16 k] fp32, 64 B rows. XOR col (16 B granule) by
// ((row>>3)&3)<<2: a wave's 8 distinct rows (stride 8) split into 4 bank
// quads x 2-way (free); 8 expert-lanes sharing a row broadcast (free).

__device__ __forceinline__ void gload16(const float* g, const float* lds) {
    __builtin_amdgcn_global_load_lds(
        (const __attribute__((address_space(1))) unsigned int*)g,
        (__attribute__((address_space(3))) unsigned int*)lds, 16, 0, 0);
}

__global__ void zero_acc(float* acc) {
    int t = threadIdx.x;
    if (t < 129) acc[t] = 0.0f;
}

__global__ __launch_bounds__(128, 4) void gemm_part(
    const float* __restrict__ x, const float* __restrict__ W,
    float* __restrict__ pws)
{
    __shared__ __align__(16) float xb[2][MT * KC];   // 2 x 8 KB, swizzled

    const int tid  = threadIdx.x;
    const int tb   = blockIdx.x & (NTOK / MT - 1);  // token block 0..127
    const int s    = blockIdx.x >> 7;               // k-split 0..7
    const int tok0 = tb * MT;
    const int kb   = s * KRANGE;

    const int tx = tid & 7;              // experts 8tx..8tx+7
    const int ty = tid >> 3;             // tokens 8ty..8ty+7
    const int e0 = tx * 8;

    // --- x staging (inverse-swizzled source) ---
    // LDS slot o = u*512 + tid*4 : row = u*32 + (tid>>2), lds col = (tid&3)*4.
    // global col = lds col ^ swz(row); swz(row)=((row>>3)&3)<<2 and
    // (row>>3)&3 = (u*4 + (tid>>5))&3 = (tid>>5)&3  -> u-invariant.
    const int srow = tid >> 2;                       // + u*32
    const int gcol = ((tid & 3) << 2) ^ (((tid >> 5) & 3) << 2);
    const float* xsrc = x + (size_t)(tok0 + srow) * DDIM + kb + gcol;

    float accv[8][8];
    #pragma unroll
    for (int t = 0; t < 8; ++t)
        #pragma unroll
        for (int j = 0; j < 8; ++j) accv[t][j] = 0.0f;

    // prologue: stage chunk 0 into buffer 0
    #pragma unroll
    for (int u = 0; u < 4; ++u)
        gload16(xsrc + (size_t)u * 32 * DDIM, &xb[0][u * 512 + tid * 4]);

    const int tr0 = ty * 8;              // first token row of this thread
    const int xsw = (ty & 3) << 2;       // swz(ty*8+t), t<8: loop-invariant

    for (int c = 0; c < NCH; ++c) {
        __syncthreads();   // drains vmcnt -> chunk c staged; prev compute done
        const int cur = c & 1;
        if (c + 1 < NCH) {
            const int nb = cur ^ 1;
            #pragma unroll
            for (int u = 0; u < 4; ++u)
                gload16(xsrc + (c + 1) * KC + (size_t)u * 32 * DDIM,
                        &xb[nb][u * 512 + tid * 4]);
        }
        const float* xcb = xb[cur];
        const float* wk  = W + (size_t)(kb + c * KC) * NEXP + e0;  // L2-resident
        #pragma unroll
        for (int s2 = 0; s2 < KC / 4; ++s2) {
            float wr[4][8];
            #pragma unroll
            for (int r = 0; r < 4; ++r) {
                const float* wrow = wk + (size_t)(4 * s2 + r) * NEXP;
                *(float4*)&wr[r][0] = *(const float4*)wrow;
                *(float4*)&wr[r][4] = *(const float4*)(wrow + 4);
            }
            #pragma unroll
            for (int t = 0; t < 8; ++t) {
                float xr[4];
                *(float4*)xr =
                    *(const float4*)&xcb[((tr0 + t) << 4) + ((4 * s2) ^ xsw)];
                #pragma unroll
                for (int r = 0; r < 4; ++r)      // k ascending per acc element
                    #pragma unroll
                    for (int j = 0; j < 8; ++j)
                        accv[t][j] = fmaf(xr[r], wr[r][j], accv[t][j]);
            }
        }
    }

    // store partial logits pws[s][tok][e], coalesced float4
    float* pb = pws + ((size_t)s * NTOK + tok0) * NEXP;
    #pragma unroll
    for (int t = 0; t < 8; ++t) {
        *(float4*)&pb[(size_t)(tr0 + t) * NEXP + e0]     = *(float4*)&accv[t][0];
        *(float4*)&pb[(size_t)(tr0 + t) * NEXP + e0 + 4] = *(float4*)&accv[t][4];
    }
}

#define ETOK 64   // tokens per epilogue block

__global__ __launch_bounds__(256) void epilogue(
    const float* __restrict__ pws, const float* __restrict__ bias,
    float* __restrict__ out, float* __restrict__ acc_g)
{
    __shared__ int   f_loc[NEXP];
    __shared__ float p_loc[NEXP];
    __shared__ float z_loc;

    const int tid = threadIdx.x;
    const int tx  = tid & 15;         // expert group: 4tx..4tx+3
    const int tg  = tid >> 4;         // token slot 0..15
    const int e0  = tx * 4;

    if (tid < NEXP) { f_loc[tid] = 0; p_loc[tid] = 0.0f; }
    if (tid == 0) z_loc = 0.0f;
    __syncthreads();

    float bb[4];
    *(float4*)bb = *(const float4*)&bias[e0];

    float pacc[4] = {0.f, 0.f, 0.f, 0.f};
    float zacc = 0.0f;

    for (int it = 0; it < ETOK / 16; ++it) {
        const int gt = blockIdx.x * ETOK + it * 16 + tg;

        // sum 8 partials in fixed ascending-s order, then + bias
        float l[4];
        {
            const size_t ro = (size_t)gt * NEXP + e0;
            float4 q[KSPLIT];
            #pragma unroll
            for (int sp = 0; sp < KSPLIT; ++sp)
                q[sp] = *(const float4*)&pws[(size_t)sp * NTOK * NEXP + ro];
            float a0 = q[0].x, a1 = q[0].y, a2 = q[0].z, a3 = q[0].w;
            #pragma unroll
            for (int sp = 1; sp < KSPLIT; ++sp) {
                a0 += q[sp].x; a1 += q[sp].y; a2 += q[sp].z; a3 += q[sp].w;
            }
            l[0] = a0 + bb[0]; l[1] = a1 + bb[1];
            l[2] = a2 + bb[2]; l[3] = a3 + bb[3];
        }

        // local top-2 (stable: ascending e, strict >)
        float v1 = l[0], v2 = -INFINITY;
        int   i1 = e0,   i2 = 0x7fffffff;
        #pragma unroll
        for (int j = 1; j < 4; ++j) {
            float v = l[j]; int e = e0 + j;
            if (v > v1)      { v2 = v1; i2 = i1; v1 = v; i1 = e; }
            else if (v > v2) { v2 = v;  i2 = e; }
        }
        // merge across the 16 lanes of this token (value desc, idx asc)
        #pragma unroll
        for (int off = 1; off < 16; off <<= 1) {
            float o1 = __shfl_xor(v1, off, 16); int oi1 = __shfl_xor(i1, off, 16);
            float o2 = __shfl_xor(v2, off, 16); int oi2 = __shfl_xor(i2, off, 16);
            if (o1 > v1 || (o1 == v1 && oi1 < i1)) {
                float cs = v1; int ci = i1;
                v1 = o1; i1 = oi1;
                if (cs > o2 || (cs == o2 && ci < oi2)) { v2 = cs; i2 = ci;  }
                else                                   { v2 = o2; i2 = oi2; }
            } else {
                if (o1 > v2 || (o1 == v2 && oi1 < i2)) { v2 = o1; i2 = oi1; }
            }
        }
        const float mx = v1;

        float sden[4], dsum = 0.0f;
        #pragma unroll
        for (int j = 0; j < 4; ++j) { sden[j] = __expf(l[j] - mx); dsum += sden[j]; }
        #pragma unroll
        for (int off = 1; off < 16; off <<= 1) dsum += __shfl_xor(dsum, off, 16);
        const float inv = 1.0f / dsum;

        float zsum = 0.0f;
        #pragma unroll
        for (int j = 0; j < 4; ++j) {
            float pj = sden[j] * inv;
            pacc[j] += pj;
            zsum += __expf(pj);
        }
        #pragma unroll
        for (int off = 1; off < 16; off <<= 1) zsum += __shfl_xor(zsum, off, 16);

        if (tx == 0) {
            const float s2 = __expf(v2 - mx);      // s1 == 1
            const float ci = 1.0f / (1.0f + s2);
            out[2 * gt]     = (float)i1;
            out[2 * gt + 1] = (float)i2;
            out[2 * NTOK + 2 * gt]     = ci;
            out[2 * NTOK + 2 * gt + 1] = s2 * ci;
            atomicAdd(&f_loc[i1], 1);
            float lse = __logf(zsum);
            zacc += lse * lse;
        }
    }

    // z: wave-reduce (only tx==0 lanes carry nonzero), one LDS atomic per wave
    #pragma unroll
    for (int off = 1; off < 64; off <<= 1) zacc += __shfl_xor(zacc, off);
    if ((tid & 63) == 0) atomicAdd(&z_loc, zacc);

    // P: fold token-groups within wave, then LDS
    #pragma unroll
    for (int j = 0; j < 4; ++j) {
        pacc[j] += __shfl_xor(pacc[j], 16);
        pacc[j] += __shfl_xor(pacc[j], 32);
    }
    if ((tid & 63) < 16) {
        #pragma unroll
        for (int j = 0; j < 4; ++j) atomicAdd(&p_loc[e0 + j], pacc[j]);
    }

    __syncthreads();
    if (tid < NEXP) {
        atomicAdd(&acc_g[64 + tid], p_loc[tid]);
        if (f_loc[tid]) atomicAdd(&acc_g[tid], (float)f_loc[tid]);
    }
    if (tid == 0) atomicAdd(&acc_g[128], z_loc);
}

__global__ void gate_finalize(const float* __restrict__ acc, float* __restrict__ out) {
    int e = threadIdx.x;  // 64 threads
    float v = acc[e] * acc[64 + e];
    #pragma unroll
    for (int off = 32; off > 0; off >>= 1) v += __shfl_down(v, off);
    if (e == 0) {
        const float NT = (float)NTOK;
        out[2 * NTOK * 2]     = 0.01f * (v / (float)NEXP) / (NT * NT);
        out[2 * NTOK * 2 + 1] = 0.1f * acc[128] / NT;
    }
}

extern "C" void kernel_launch(void* const* d_in, const int* in_sizes, int n_in,
                              void* d_out, int out_size, void* d_ws, size_t ws_size,
                              hipStream_t stream) {
    const float* x    = (const float*)d_in[0];
    const float* W    = (const float*)d_in[1];
    const float* bias = (const float*)d_in[2];
    float* out = (float*)d_out;
    float* acc = (float*)d_ws;
    float* pws = acc + PART_OFF;

    zero_acc<<<1, 256, 0, stream>>>(acc);
    gemm_part<<<KSPLIT * (NTOK / MT), 128, 0, stream>>>(x, W, pws);
    epilogue<<<NTOK / ETOK, 256, 0, stream>>>(pws, bias, out, acc);
    gate_finalize<<<1, 64, 0, stream>>>(acc, out);
}

// Round 9
// 103.913 us; speedup vs baseline: 1.2780x; 1.2780x over previous
//
#include <hip/hip_runtime.h>
#include <math.h>

#define NTOK 16384
#define DDIM 2048
#define NEXP 64
#define MT   128                 // tokens per stage-1 block
#define KSPLIT 8
#define KRANGE (DDIM / KSPLIT)   // 256
#define KC   16                  // k per LDS chunk
#define NCH  (KRANGE / KC)       // 16

// ws layout (floats): [0..63] f counts, [64..127] P sums, [128] sum lse^2,
// [256 ...] partial logits: [KSPLIT][NTOK][NEXP]
#define PART_OFF 256

// x-tile LDS: [128 tok][16 k] fp32, 64 B rows. A wave's xr read touches 8
// rows at stride 4 (rows 4*ty+t, ty = 8w..8w+7): 16*row mod 32 depends only
// on t -> 8-way bank conflict if linear. XOR the 16 B granule by (ty&3):
// 4 distinct quads x 2-way (free).   Inverse applied on gload source.

__device__ __forceinline__ void gload16(const float* g, const float* lds) {
    __builtin_amdgcn_global_load_lds(
        (const __attribute__((address_space(1))) unsigned int*)g,
        (__attribute__((address_space(3))) unsigned int*)lds, 16, 0, 0);
}

__global__ void zero_acc(float* acc) {
    int t = threadIdx.x;
    if (t < 129) acc[t] = 0.0f;
}

__global__ __launch_bounds__(256, 4) void gemm_part(
    const float* __restrict__ x, const float* __restrict__ W,
    float* __restrict__ pws)
{
    __shared__ __align__(16) float xb[2][MT * KC];   // 2 x 8 KB, swizzled

    const int tid  = threadIdx.x;
    const int tb   = blockIdx.x & (NTOK / MT - 1);  // token block 0..127
    const int s    = blockIdx.x >> 7;               // k-split 0..7
    const int tok0 = tb * MT;
    const int kb   = s * KRANGE;

    const int tx = tid & 7;              // experts 8tx..8tx+7
    const int ty = tid >> 3;             // tokens 4ty..4ty+3 (0..31)
    const int e0 = tx * 8;

    // --- x staging (inverse-swizzled source) ---
    // LDS slot o = u*1024 + tid*4 dwords: row = u*64 + (tid>>2),
    // lds granule = tid&3. global granule = (tid&3) ^ ((row>>2)&3);
    // (row>>2)&3 = ((tid>>4) + u*16)&3 = (tid>>4)&3  -> u-invariant.
    const int srow = tid >> 2;                               // + u*64
    const int gcol = (((tid & 3) ^ ((tid >> 4) & 3))) << 2;  // dword col
    const float* xsrc = x + (size_t)(tok0 + srow) * DDIM + kb + gcol;

    float accv[4][8];
    #pragma unroll
    for (int t = 0; t < 4; ++t)
        #pragma unroll
        for (int j = 0; j < 8; ++j) accv[t][j] = 0.0f;

    // prologue: stage chunk 0 into buffer 0
    gload16(xsrc,                      &xb[0][tid * 4]);
    gload16(xsrc + (size_t)64 * DDIM,  &xb[0][1024 + tid * 4]);

    const int tr0 = ty * 4;              // first token row of this thread
    const int xsw = ty & 3;              // read-granule XOR, loop-invariant

    for (int c = 0; c < NCH; ++c) {
        __syncthreads();   // drains vmcnt -> chunk c staged; prev compute done
        const int cur = c & 1;
        if (c + 1 < NCH) {
            const int nb = cur ^ 1;
            const int ko = (c + 1) * KC;
            gload16(xsrc + ko,                     &xb[nb][tid * 4]);
            gload16(xsrc + ko + (size_t)64 * DDIM, &xb[nb][1024 + tid * 4]);
        }
        const float* xcb = xb[cur];
        const float* wk  = W + (size_t)(kb + c * KC) * NEXP + e0; // L2-resident
        #pragma unroll
        for (int s2 = 0; s2 < KC / 4; ++s2) {
            float wr[4][8];
            #pragma unroll
            for (int r = 0; r < 4; ++r) {
                const float* wrow = wk + (size_t)(4 * s2 + r) * NEXP;
                *(float4*)&wr[r][0] = *(const float4*)wrow;
                *(float4*)&wr[r][4] = *(const float4*)(wrow + 4);
            }
            float xr[4][4];
            #pragma unroll
            for (int t = 0; t < 4; ++t)
                *(float4*)xr[t] = *(const float4*)
                    &xcb[((tr0 + t) << 4) + ((s2 ^ xsw) << 2)];
            #pragma unroll
            for (int r = 0; r < 4; ++r)      // k ascending per acc element
                #pragma unroll
                for (int t = 0; t < 4; ++t)
                    #pragma unroll
                    for (int j = 0; j < 8; ++j)
                        accv[t][j] = fmaf(xr[t][r], wr[r][j], accv[t][j]);
        }
    }

    // store partial logits pws[s][tok][e], coalesced float4
    float* pb = pws + ((size_t)s * NTOK + tok0) * NEXP;
    #pragma unroll
    for (int t = 0; t < 4; ++t) {
        *(float4*)&pb[(size_t)(tr0 + t) * NEXP + e0]     = *(float4*)&accv[t][0];
        *(float4*)&pb[(size_t)(tr0 + t) * NEXP + e0 + 4] = *(float4*)&accv[t][4];
    }
}

#define ETOK 64   // tokens per epilogue block

__global__ __launch_bounds__(256) void epilogue(
    const float* __restrict__ pws, const float* __restrict__ bias,
    float* __restrict__ out, float* __restrict__ acc_g)
{
    __shared__ int   f_loc[NEXP];
    __shared__ float p_loc[NEXP];
    __shared__ float z_loc;

    const int tid = threadIdx.x;
    const int tx  = tid & 15;         // expert group: 4tx..4tx+3
    const int tg  = tid >> 4;         // token slot 0..15
    const int e0  = tx * 4;

    if (tid < NEXP) { f_loc[tid] = 0; p_loc[tid] = 0.0f; }
    if (tid == 0) z_loc = 0.0f;
    __syncthreads();

    float bb[4];
    *(float4*)bb = *(const float4*)&bias[e0];

    float pacc[4] = {0.f, 0.f, 0.f, 0.f};
    float zacc = 0.0f;

    for (int it = 0; it < ETOK / 16; ++it) {
        const int gt = blockIdx.x * ETOK + it * 16 + tg;

        // sum 8 partials in fixed ascending-s order, then + bias
        float l[4];
        {
            const size_t ro = (size_t)gt * NEXP + e0;
            float4 q[KSPLIT];
            #pragma unroll
            for (int sp = 0; sp < KSPLIT; ++sp)
                q[sp] = *(const float4*)&pws[(size_t)sp * NTOK * NEXP + ro];
            float a0 = q[0].x, a1 = q[0].y, a2 = q[0].z, a3 = q[0].w;
            #pragma unroll
            for (int sp = 1; sp < KSPLIT; ++sp) {
                a0 += q[sp].x; a1 += q[sp].y; a2 += q[sp].z; a3 += q[sp].w;
            }
            l[0] = a0 + bb[0]; l[1] = a1 + bb[1];
            l[2] = a2 + bb[2]; l[3] = a3 + bb[3];
        }

        // local top-2 (stable: ascending e, strict >)
        float v1 = l[0], v2 = -INFINITY;
        int   i1 = e0,   i2 = 0x7fffffff;
        #pragma unroll
        for (int j = 1; j < 4; ++j) {
            float v = l[j]; int e = e0 + j;
            if (v > v1)      { v2 = v1; i2 = i1; v1 = v; i1 = e; }
            else if (v > v2) { v2 = v;  i2 = e; }
        }
        // merge across the 16 lanes of this token (value desc, idx asc)
        #pragma unroll
        for (int off = 1; off < 16; off <<= 1) {
            float o1 = __shfl_xor(v1, off, 16); int oi1 = __shfl_xor(i1, off, 16);
            float o2 = __shfl_xor(v2, off, 16); int oi2 = __shfl_xor(i2, off, 16);
            if (o1 > v1 || (o1 == v1 && oi1 < i1)) {
                float cs = v1; int ci = i1;
                v1 = o1; i1 = oi1;
                if (cs > o2 || (cs == o2 && ci < oi2)) { v2 = cs; i2 = ci;  }
                else                                   { v2 = o2; i2 = oi2; }
            } else {
                if (o1 > v2 || (o1 == v2 && oi1 < i2)) { v2 = o1; i2 = oi1; }
            }
        }
        const float mx = v1;

        float sden[4], dsum = 0.0f;
        #pragma unroll
        for (int j = 0; j < 4; ++j) { sden[j] = __expf(l[j] - mx); dsum += sden[j]; }
        #pragma unroll
        for (int off = 1; off < 16; off <<= 1) dsum += __shfl_xor(dsum, off, 16);
        const float inv = 1.0f / dsum;

        float zsum = 0.0f;
        #pragma unroll
        for (int j = 0; j < 4; ++j) {
            float pj = sden[j] * inv;
            pacc[j] += pj;
            zsum += __expf(pj);
        }
        #pragma unroll
        for (int off = 1; off < 16; off <<= 1) zsum += __shfl_xor(zsum, off, 16);

        if (tx == 0) {
            const float s2 = __expf(v2 - mx);      // s1 == 1
            const float ci = 1.0f / (1.0f + s2);
            out[2 * gt]     = (float)i1;
            out[2 * gt + 1] = (float)i2;
            out[2 * NTOK + 2 * gt]     = ci;
            out[2 * NTOK + 2 * gt + 1] = s2 * ci;
            atomicAdd(&f_loc[i1], 1);
            float lse = __logf(zsum);
            zacc += lse * lse;
        }
    }

    // z: wave-reduce (only tx==0 lanes carry nonzero), one LDS atomic per wave
    #pragma unroll
    for (int off = 1; off < 64; off <<= 1) zacc += __shfl_xor(zacc, off);
    if ((tid & 63) == 0) atomicAdd(&z_loc, zacc);

    // P: fold token-groups within wave, then LDS
    #pragma unroll
    for (int j = 0; j < 4; ++j) {
        pacc[j] += __shfl_xor(pacc[j], 16);
        pacc[j] += __shfl_xor(pacc[j], 32);
    }
    if ((tid & 63) < 16) {
        #pragma unroll
        for (int j = 0; j < 4; ++j) atomicAdd(&p_loc[e0 + j], pacc[j]);
    }

    __syncthreads();
    if (tid < NEXP) {
        atomicAdd(&acc_g[64 + tid], p_loc[tid]);
        if (f_loc[tid]) atomicAdd(&acc_g[tid], (float)f_loc[tid]);
    }
    if (tid == 0) atomicAdd(&acc_g[128], z_loc);
}

__global__ void gate_finalize(const float* __restrict__ acc, float* __restrict__ out) {
    int e = threadIdx.x;  // 64 threads
    float v = acc[e] * acc[64 + e];
    #pragma unroll
    for (int off = 32; off > 0; off >>= 1) v += __shfl_down(v, off);
    if (e == 0) {
        const float NT = (float)NTOK;
        out[2 * NTOK * 2]     = 0.01f * (v / (float)NEXP) / (NT * NT);
        out[2 * NTOK * 2 + 1] = 0.1f * acc[128] / NT;
    }
}

extern "C" void kernel_launch(void* const* d_in, const int* in_sizes, int n_in,
                              void* d_out, int out_size, void* d_ws, size_t ws_size,
                              hipStream_t stream) {
    const float* x    = (const float*)d_in[0];
    const float* W    = (const float*)d_in[1];
    const float* bias = (const float*)d_in[2];
    float* out = (float*)d_out;
    float* acc = (float*)d_ws;
    float* pws = acc + PART_OFF;

    zero_acc<<<1, 256, 0, stream>>>(acc);
    gemm_part<<<KSPLIT * (NTOK / MT), 256, 0, stream>>>(x, W, pws);
    epilogue<<<NTOK / ETOK, 256, 0, stream>>>(pws, bias, out, acc);
    gate_finalize<<<1, 64, 0, stream>>>(acc, out);
}